// Round 1
// baseline (522.165 us; speedup 1.0000x reference)
//
#include <hip/hip_runtime.h>
#include <hip/hip_bf16.h>

#define S_LEN 4096
#define EMBED 512
#define HEADS 8
#define HD    64
#define KVB   64

typedef short v8s __attribute__((ext_vector_type(8)));   // 8 bf16 in 4 VGPRs
typedef float v4f __attribute__((ext_vector_type(4)));
typedef unsigned short u16;

// ws layout (bytes)
#define OFF_Q   0u
#define OFF_K   8388608u
#define OFF_VT  16777216u
#define OFF_AT  25165824u
#define OFF_WO  33554432u

static __device__ __forceinline__ short f2bf(float f) {
    __hip_bfloat16 h = __float2bfloat16(f);
    return __builtin_bit_cast(short, h);
}

static __device__ __forceinline__ v8s load8f_bf(const float* __restrict__ p) {
    float4 a = reinterpret_cast<const float4*>(p)[0];
    float4 b = reinterpret_cast<const float4*>(p)[1];
    v8s r;
    r[0]=f2bf(a.x); r[1]=f2bf(a.y); r[2]=f2bf(a.z); r[3]=f2bf(a.w);
    r[4]=f2bf(b.x); r[5]=f2bf(b.y); r[6]=f2bf(b.z); r[7]=f2bf(b.w);
    return r;
}

// ---------------------------------------------------------------------------
// Kernel 1: per-head QKV projections (bf16 MFMA), V written TRANSPOSED.
// grid 1024 = (b,h) x (s-tile of 64); 4 waves, each 16 s-rows.
// Q gets scale log2(e)/sqrt(512) folded in (softmax runs in exp2 domain).
// Also casts Wo -> bf16 (1024*256 == 512*512 exactly).
// ---------------------------------------------------------------------------
__global__ __launch_bounds__(256) void proj_kernel(
    const float* __restrict__ xv, const float* __restrict__ xk,
    const float* __restrict__ xq,
    const float* __restrict__ Wv, const float* __restrict__ Wk,
    const float* __restrict__ Wq, const float* __restrict__ Wo,
    u16* __restrict__ q_bf, u16* __restrict__ k_bf,
    u16* __restrict__ vt_bf, u16* __restrict__ wo_bf)
{
    const int tid = threadIdx.x;
    const int lane = tid & 63;
    const int w = tid >> 6;
    const int lr = lane & 15;
    const int g  = lane >> 4;
    const int bid = blockIdx.x;
    const int bh = bid >> 6;          // b*8+h
    const int stile = bid & 63;
    const int b = bh >> 3, h = bh & 7;
    const int s0 = stile * 64;

    // Wo -> bf16
    {
        int idx = bid * 256 + tid;
        wo_bf[idx] = (u16)f2bf(Wo[idx]);
    }

    const int srow = s0 + w*16 + lr;
    const size_t xbase = ((size_t)b*S_LEN + srow)*EMBED + h*HD;
    v8s aq0 = load8f_bf(xq + xbase + g*8);
    v8s aq1 = load8f_bf(xq + xbase + 32 + g*8);
    v8s ak0 = load8f_bf(xk + xbase + g*8);
    v8s ak1 = load8f_bf(xk + xbase + 32 + g*8);
    v8s av0 = load8f_bf(xv + xbase + g*8);
    v8s av1 = load8f_bf(xv + xbase + 32 + g*8);

    const float qscale = 1.44269504088896f / 22.6274169979695f; // log2(e)/sqrt(512)
    const size_t obase = (size_t)bh * S_LEN * HD;

    // Q projection: out[s][e] = sum_d X[s][d] Wq[e][d]
#pragma unroll
    for (int et = 0; et < 4; ++et) {
        v4f acc = (v4f){0.f,0.f,0.f,0.f};
        v8s b0 = load8f_bf(Wq + (et*16 + lr)*HD + g*8);
        v8s b1 = load8f_bf(Wq + (et*16 + lr)*HD + 32 + g*8);
        acc = __builtin_amdgcn_mfma_f32_16x16x32_bf16(aq0, b0, acc, 0,0,0);
        acc = __builtin_amdgcn_mfma_f32_16x16x32_bf16(aq1, b1, acc, 0,0,0);
#pragma unroll
        for (int r = 0; r < 4; ++r) {
            int so = s0 + w*16 + g*4 + r;
            q_bf[obase + (size_t)so*HD + et*16 + lr] = (u16)f2bf(acc[r]*qscale);
        }
    }
    // K projection
#pragma unroll
    for (int et = 0; et < 4; ++et) {
        v4f acc = (v4f){0.f,0.f,0.f,0.f};
        v8s b0 = load8f_bf(Wk + (et*16 + lr)*HD + g*8);
        v8s b1 = load8f_bf(Wk + (et*16 + lr)*HD + 32 + g*8);
        acc = __builtin_amdgcn_mfma_f32_16x16x32_bf16(ak0, b0, acc, 0,0,0);
        acc = __builtin_amdgcn_mfma_f32_16x16x32_bf16(ak1, b1, acc, 0,0,0);
#pragma unroll
        for (int r = 0; r < 4; ++r) {
            int so = s0 + w*16 + g*4 + r;
            k_bf[obase + (size_t)so*HD + et*16 + lr] = (u16)f2bf(acc[r]);
        }
    }
    // V projection, SWAPPED: VT[e][s] = sum_d Wv[e][d] X[s][d]  (A=Wv, B=X^T)
    // -> coalesced transposed write (32B per (et,reg) across 16 lanes)
#pragma unroll
    for (int et = 0; et < 4; ++et) {
        v4f acc = (v4f){0.f,0.f,0.f,0.f};
        v8s a0 = load8f_bf(Wv + (et*16 + lr)*HD + g*8);
        v8s a1 = load8f_bf(Wv + (et*16 + lr)*HD + 32 + g*8);
        acc = __builtin_amdgcn_mfma_f32_16x16x32_bf16(a0, av0, acc, 0,0,0);
        acc = __builtin_amdgcn_mfma_f32_16x16x32_bf16(a1, av1, acc, 0,0,0);
#pragma unroll
        for (int r = 0; r < 4; ++r) {
            int e = et*16 + g*4 + r;
            vt_bf[obase + (size_t)e*S_LEN + s0 + w*16 + lr] = (u16)f2bf(acc[r]);
        }
    }
}

// ---------------------------------------------------------------------------
// Kernel 2: flash attention. grid 1024 = (b,h) x (q-tile of 64), XCD-swizzled
// so each XCD's L2 holds only 2 heads' K/V (2 MB < 4 MB). 4 independent
// waves (16 q-rows each), KVB=64, online softmax in exp2 domain.
// P goes through a per-wave XOR-swizzled LDS buffer to become the PV A-frag.
// ---------------------------------------------------------------------------
__global__ __launch_bounds__(256) void flash_kernel(
    const u16* __restrict__ q_bf, const u16* __restrict__ k_bf,
    const u16* __restrict__ vt_bf, u16* __restrict__ attn_buf)
{
    __shared__ alignas(16) char p_smem[4 * 16 * KVB * 2];  // 8 KiB

    const int tid = threadIdx.x;
    const int lane = tid & 63;
    const int w = tid >> 6;
    const int lr = lane & 15;
    const int g  = lane >> 4;

    // bijective XCD swizzle (nwg=1024, %8==0)
    const int orig = blockIdx.x;
    const int wg = (orig & 7) * 128 + (orig >> 3);
    const int bh = wg >> 6;
    const int qtile = wg & 63;
    const int s0 = qtile*64 + w*16;

    const u16* Q  = q_bf  + (size_t)bh * S_LEN * HD;
    const u16* K  = k_bf  + (size_t)bh * S_LEN * HD;
    const u16* VT = vt_bf + (size_t)bh * HD * S_LEN;

    // Q A-frags (pre-scaled by log2(e)/sqrt(512))
    v8s qf0 = *(const v8s*)(Q + (size_t)(s0+lr)*HD + g*8);
    v8s qf1 = *(const v8s*)(Q + (size_t)(s0+lr)*HD + 32 + g*8);

    v4f o[4];
#pragma unroll
    for (int i = 0; i < 4; ++i) o[i] = (v4f){0.f,0.f,0.f,0.f};
    float mrow[4] = {-INFINITY,-INFINITY,-INFINITY,-INFINITY};
    float lrow[4] = {0.f,0.f,0.f,0.f};

    char* pbase = p_smem + w * (16*KVB*2);

    for (int kb = 0; kb < S_LEN/KVB; ++kb) {
        const int kv0 = kb * KVB;
        // QK^T: 4 kv-tiles x 2 d-chunks
        v4f st[4];
#pragma unroll
        for (int t = 0; t < 4; ++t) {
            const u16* kp = K + (size_t)(kv0 + t*16 + lr)*HD + g*8;
            v8s kf0 = *(const v8s*)(kp);
            v8s kf1 = *(const v8s*)(kp + 32);
            v4f acc = (v4f){0.f,0.f,0.f,0.f};
            acc = __builtin_amdgcn_mfma_f32_16x16x32_bf16(qf0, kf0, acc, 0,0,0);
            acc = __builtin_amdgcn_mfma_f32_16x16x32_bf16(qf1, kf1, acc, 0,0,0);
            st[t] = acc;
        }
        // online softmax; rows 4g+r live in the 16-lane group g
#pragma unroll
        for (int r = 0; r < 4; ++r) {
            float tmax = fmaxf(fmaxf(st[0][r], st[1][r]), fmaxf(st[2][r], st[3][r]));
            tmax = fmaxf(tmax, __shfl_xor(tmax, 1));
            tmax = fmaxf(tmax, __shfl_xor(tmax, 2));
            tmax = fmaxf(tmax, __shfl_xor(tmax, 4));
            tmax = fmaxf(tmax, __shfl_xor(tmax, 8));
            float mnew = fmaxf(mrow[r], tmax);
            float corr = __builtin_amdgcn_exp2f(mrow[r] - mnew);
            mrow[r] = mnew;
            const int row = g*4 + r;
            const int swz = (row & 7) << 4;
            float psum = 0.f;
#pragma unroll
            for (int t = 0; t < 4; ++t) {
                float p = __builtin_amdgcn_exp2f(st[t][r] - mnew);
                psum += p;
                int byteoff = (row*128 + (t*16 + lr)*2) ^ swz;
                *(u16*)(pbase + byteoff) = (u16)f2bf(p);
            }
            psum += __shfl_xor(psum, 1);
            psum += __shfl_xor(psum, 2);
            psum += __shfl_xor(psum, 4);
            psum += __shfl_xor(psum, 8);
            lrow[r] = lrow[r]*corr + psum;
#pragma unroll
            for (int dt = 0; dt < 4; ++dt) o[dt][r] *= corr;
        }
        // P A-frags from swizzled LDS (chunk pc: kv 32*pc + 8g + j)
        v8s pf0, pf1;
        {
            int b0 = (lr*128 + g*16 +  0) ^ ((lr & 7) << 4);
            int b1 = (lr*128 + g*16 + 64) ^ ((lr & 7) << 4);
            pf0 = *(const v8s*)(pbase + b0);
            pf1 = *(const v8s*)(pbase + b1);
        }
        // PV: o[dt] += P * V   (B-frag from VT, contiguous along kv)
#pragma unroll
        for (int dt = 0; dt < 4; ++dt) {
            const u16* vp = VT + (size_t)(dt*16 + lr)*S_LEN + kv0 + g*8;
            v8s vf0 = *(const v8s*)(vp);
            v8s vf1 = *(const v8s*)(vp + 32);
            o[dt] = __builtin_amdgcn_mfma_f32_16x16x32_bf16(pf0, vf0, o[dt], 0,0,0);
            o[dt] = __builtin_amdgcn_mfma_f32_16x16x32_bf16(pf1, vf1, o[dt], 0,0,0);
        }
    }

    // epilogue: normalize and write attn_buf[b][s][h*64+d] (bf16)
    const int b = bh >> 3, h = bh & 7;
#pragma unroll
    for (int r = 0; r < 4; ++r) {
        float inv = __builtin_amdgcn_rcpf(lrow[r]);
        int srow = s0 + g*4 + r;
#pragma unroll
        for (int dt = 0; dt < 4; ++dt) {
            attn_buf[((size_t)b*S_LEN + srow)*EMBED + h*HD + dt*16 + lr] =
                (u16)f2bf(o[dt][r] * inv);
        }
    }
}

// ---------------------------------------------------------------------------
// Kernel 3: out = attn_buf @ Wo^T + bo  (M=8192, N=512, K=512), fp32 out.
// grid 1024 = 128 m-tiles x 8 n-tiles; 4 waves, each 16m x 64n.
// ---------------------------------------------------------------------------
__global__ __launch_bounds__(256) void oproj_kernel(
    const u16* __restrict__ attn_buf, const u16* __restrict__ wo_bf,
    const float* __restrict__ bo, float* __restrict__ out)
{
    const int tid = threadIdx.x;
    const int lane = tid & 63;
    const int w = tid >> 6;
    const int lr = lane & 15;
    const int g  = lane >> 4;
    const int bid = blockIdx.x;
    const int m0 = (bid >> 3)*64 + w*16;
    const int n0 = (bid & 7)*64;

    v4f acc[4];
#pragma unroll
    for (int i = 0; i < 4; ++i) acc[i] = (v4f){0.f,0.f,0.f,0.f};

    for (int kk = 0; kk < EMBED/32; ++kk) {
        const int k0 = kk*32;
        v8s af = *(const v8s*)(attn_buf + (size_t)(m0+lr)*EMBED + k0 + g*8);
#pragma unroll
        for (int nt = 0; nt < 4; ++nt) {
            v8s bf = *(const v8s*)(wo_bf + (size_t)(n0 + nt*16 + lr)*EMBED + k0 + g*8);
            acc[nt] = __builtin_amdgcn_mfma_f32_16x16x32_bf16(af, bf, acc[nt], 0,0,0);
        }
    }
#pragma unroll
    for (int nt = 0; nt < 4; ++nt) {
        float bias = bo[n0 + nt*16 + lr];
#pragma unroll
        for (int r = 0; r < 4; ++r) {
            out[(size_t)(m0 + g*4 + r)*EMBED + n0 + nt*16 + lr] = acc[nt][r] + bias;
        }
    }
}

extern "C" void kernel_launch(void* const* d_in, const int* in_sizes, int n_in,
                              void* d_out, int out_size, void* d_ws, size_t ws_size,
                              hipStream_t stream)
{
    const float* xv = (const float*)d_in[0];   // values
    const float* xk = (const float*)d_in[1];   // keys
    const float* xq = (const float*)d_in[2];   // query
    const float* Wv = (const float*)d_in[3];
    const float* Wk = (const float*)d_in[4];
    const float* Wq = (const float*)d_in[5];
    const float* Wo = (const float*)d_in[6];
    const float* bo = (const float*)d_in[7];

    char* ws = (char*)d_ws;
    u16* q_bf   = (u16*)(ws + OFF_Q);
    u16* k_bf   = (u16*)(ws + OFF_K);
    u16* vt_bf  = (u16*)(ws + OFF_VT);
    u16* at_buf = (u16*)(ws + OFF_AT);
    u16* wo_bf  = (u16*)(ws + OFF_WO);

    proj_kernel<<<1024, 256, 0, stream>>>(xv, xk, xq, Wv, Wk, Wq, Wo,
                                          q_bf, k_bf, vt_bf, wo_bf);
    flash_kernel<<<1024, 256, 0, stream>>>(q_bf, k_bf, vt_bf, at_buf);
    oproj_kernel<<<1024, 256, 0, stream>>>(at_buf, wo_bf, bo, (float*)d_out);
}

// Round 3
// 302.354 us; speedup vs baseline: 1.7270x; 1.7270x over previous
//
#include <hip/hip_runtime.h>
#include <hip/hip_bf16.h>

#define S_LEN 4096
#define EMBED 512
#define HEADS 8
#define HD    64

typedef short v8s __attribute__((ext_vector_type(8)));   // 8 bf16 in 4 VGPRs
typedef float v4f __attribute__((ext_vector_type(4)));
typedef float v16f __attribute__((ext_vector_type(16)));
typedef unsigned int v4u __attribute__((ext_vector_type(4)));
typedef unsigned short u16;
typedef unsigned short v4us __attribute__((ext_vector_type(4)));

// ws layout (bytes)
#define OFF_Q   0u
#define OFF_K   8388608u
#define OFF_VT  16777216u
#define OFF_AT  25165824u
#define OFF_WO  33554432u

static __device__ __forceinline__ short f2bf(float f) {
    __hip_bfloat16 h = __float2bfloat16(f);
    return __builtin_bit_cast(short, h);
}

static __device__ __forceinline__ v8s load8f_bf(const float* __restrict__ p) {
    float4 a = reinterpret_cast<const float4*>(p)[0];
    float4 b = reinterpret_cast<const float4*>(p)[1];
    v8s r;
    r[0]=f2bf(a.x); r[1]=f2bf(a.y); r[2]=f2bf(a.z); r[3]=f2bf(a.w);
    r[4]=f2bf(b.x); r[5]=f2bf(b.y); r[6]=f2bf(b.z); r[7]=f2bf(b.w);
    return r;
}

static __device__ __forceinline__ v16f zero16() {
    v16f z;
#pragma unroll
    for (int i = 0; i < 16; ++i) z[i] = 0.f;
    return z;
}

// pack two f32 -> u32 of 2 bf16 (low = lo, high = hi)
static __device__ __forceinline__ unsigned cvtpk(float lo, float hi) {
    unsigned r;
    asm volatile("v_cvt_pk_bf16_f32 %0, %1, %2" : "=v"(r) : "v"(lo), "v"(hi));
    return r;
}

// swap a's high 32 lanes with b's low 32 lanes
static __device__ __forceinline__ void pl32swap(unsigned &a, unsigned &b) {
    asm volatile("v_permlane32_swap_b32 %0, %1" : "+v"(a), "+v"(b));
}

// ---------------------------------------------------------------------------
// Kernel 1: per-head QKV projections (bf16 MFMA), V written TRANSPOSED.
// grid 1024 = (b,h) x (s-tile of 64); 4 waves, each 16 s-rows.
// Q gets scale log2(e)/sqrt(512) folded in (softmax runs in exp2 domain).
// Also casts Wo -> bf16.
// ---------------------------------------------------------------------------
__global__ __launch_bounds__(256) void proj_kernel(
    const float* __restrict__ xv, const float* __restrict__ xk,
    const float* __restrict__ xq,
    const float* __restrict__ Wv, const float* __restrict__ Wk,
    const float* __restrict__ Wq, const float* __restrict__ Wo,
    u16* __restrict__ q_bf, u16* __restrict__ k_bf,
    u16* __restrict__ vt_bf, u16* __restrict__ wo_bf)
{
    const int tid = threadIdx.x;
    const int lane = tid & 63;
    const int w = tid >> 6;
    const int lr = lane & 15;
    const int g  = lane >> 4;
    const int bid = blockIdx.x;
    const int bh = bid >> 6;          // b*8+h
    const int stile = bid & 63;
    const int b = bh >> 3, h = bh & 7;
    const int s0 = stile * 64;

    // Wo -> bf16
    {
        int idx = bid * 256 + tid;
        wo_bf[idx] = (u16)f2bf(Wo[idx]);
    }

    const int srow = s0 + w*16 + lr;
    const size_t xbase = ((size_t)b*S_LEN + srow)*EMBED + h*HD;
    v8s aq0 = load8f_bf(xq + xbase + g*8);
    v8s aq1 = load8f_bf(xq + xbase + 32 + g*8);
    v8s ak0 = load8f_bf(xk + xbase + g*8);
    v8s ak1 = load8f_bf(xk + xbase + 32 + g*8);
    v8s av0 = load8f_bf(xv + xbase + g*8);
    v8s av1 = load8f_bf(xv + xbase + 32 + g*8);

    const float qscale = 1.44269504088896f / 22.6274169979695f; // log2(e)/sqrt(512)
    const size_t obase = (size_t)bh * S_LEN * HD;

    // Q projection: out[s][e] = sum_d X[s][d] Wq[e][d]
#pragma unroll
    for (int et = 0; et < 4; ++et) {
        v4f acc = (v4f){0.f,0.f,0.f,0.f};
        v8s b0 = load8f_bf(Wq + (et*16 + lr)*HD + g*8);
        v8s b1 = load8f_bf(Wq + (et*16 + lr)*HD + 32 + g*8);
        acc = __builtin_amdgcn_mfma_f32_16x16x32_bf16(aq0, b0, acc, 0,0,0);
        acc = __builtin_amdgcn_mfma_f32_16x16x32_bf16(aq1, b1, acc, 0,0,0);
#pragma unroll
        for (int r = 0; r < 4; ++r) {
            int so = s0 + w*16 + g*4 + r;
            q_bf[obase + (size_t)so*HD + et*16 + lr] = (u16)f2bf(acc[r]*qscale);
        }
    }
    // K projection
#pragma unroll
    for (int et = 0; et < 4; ++et) {
        v4f acc = (v4f){0.f,0.f,0.f,0.f};
        v8s b0 = load8f_bf(Wk + (et*16 + lr)*HD + g*8);
        v8s b1 = load8f_bf(Wk + (et*16 + lr)*HD + 32 + g*8);
        acc = __builtin_amdgcn_mfma_f32_16x16x32_bf16(ak0, b0, acc, 0,0,0);
        acc = __builtin_amdgcn_mfma_f32_16x16x32_bf16(ak1, b1, acc, 0,0,0);
#pragma unroll
        for (int r = 0; r < 4; ++r) {
            int so = s0 + w*16 + g*4 + r;
            k_bf[obase + (size_t)so*HD + et*16 + lr] = (u16)f2bf(acc[r]);
        }
    }
    // V projection, SWAPPED: VT[e][s] = sum_d Wv[e][d] X[s][d]
#pragma unroll
    for (int et = 0; et < 4; ++et) {
        v4f acc = (v4f){0.f,0.f,0.f,0.f};
        v8s a0 = load8f_bf(Wv + (et*16 + lr)*HD + g*8);
        v8s a1 = load8f_bf(Wv + (et*16 + lr)*HD + 32 + g*8);
        acc = __builtin_amdgcn_mfma_f32_16x16x32_bf16(a0, av0, acc, 0,0,0);
        acc = __builtin_amdgcn_mfma_f32_16x16x32_bf16(a1, av1, acc, 0,0,0);
#pragma unroll
        for (int r = 0; r < 4; ++r) {
            int e = et*16 + g*4 + r;
            vt_bf[obase + (size_t)e*S_LEN + s0 + w*16 + lr] = (u16)f2bf(acc[r]);
        }
    }
}

// ---------------------------------------------------------------------------
// Kernel 2: flash attention, swapped-QK^T 32x32x16 structure.
// grid 512 = (b,h) x (q-tile of 128); 4 independent waves, 32 q-rows each.
// S^T = mfma(K, Q): lane holds S[kv-slice][q = lane&31] -> softmax fully
// in-register (1 shfl_xor(32) for max, 1 for sum).
// P -> bf16 B-frags via v_cvt_pk_bf16_f32 + v_permlane32_swap_b32 (T12).
// PV accumulated TRANSPOSED: O^T = mfma(A=V^T, B=P^T) so the accumulator's
// q is lane-local (col = lane&31) and the online rescale by `corr` (per-lane,
// q = lane&31) is correct -- this fixes round 2's bug where o-rows spanned
// different q per register while corr was per-lane.
// No LDS, no barriers.
// ---------------------------------------------------------------------------
__global__ __launch_bounds__(256) void flash_kernel(
    const u16* __restrict__ q_bf, const u16* __restrict__ k_bf,
    const u16* __restrict__ vt_bf, u16* __restrict__ attn_buf)
{
    const int tid = threadIdx.x;
    const int lane = tid & 63;
    const int w = tid >> 6;
    const int l31 = lane & 31;
    const int hi = lane >> 5;

    // bijective XCD swizzle (nwg=512, %8==0): 64 consecutive wg per XCD
    // -> 2 heads per XCD -> K+VT (2 MB) fit the 4 MB XCD L2.
    const int orig = blockIdx.x;
    const int wg = (orig & 7) * 64 + (orig >> 3);
    const int bh = wg >> 5;
    const int qt = wg & 31;
    const int s0 = qt * 128 + w * 32;

    const u16* __restrict__ Q  = q_bf  + (size_t)bh * S_LEN * HD;
    const u16* __restrict__ K  = k_bf  + (size_t)bh * S_LEN * HD;
    const u16* __restrict__ VT = vt_bf + (size_t)bh * HD * S_LEN;

    // Q B-frags (held for the whole kernel): col q=l31, k=d chunk
    v8s qf[4];
#pragma unroll
    for (int dc = 0; dc < 4; ++dc)
        qf[dc] = *(const v8s*)(Q + (size_t)(s0 + l31)*HD + dc*16 + hi*8);

    v16f o0 = zero16(), o1 = zero16();   // O^T: rows d 0-31 / 32-63, col q=l31
    float m = -1.0e30f, lsum = 0.f;

    for (int kb = 0; kb < S_LEN/64; ++kb) {
        const int kv0 = kb * 64;

        // K A-frags: 2 kv-tiles x 4 d-chunks (row kv = tile*32 + l31)
        const u16* k0p = K + (size_t)(kv0 + l31)*HD + hi*8;
        const u16* k1p = K + (size_t)(kv0 + 32 + l31)*HD + hi*8;
        v8s kf0[4], kf1[4];
#pragma unroll
        for (int dc = 0; dc < 4; ++dc) {
            kf0[dc] = *(const v8s*)(k0p + dc*16);
            kf1[dc] = *(const v8s*)(k1p + dc*16);
        }
        // V^T A-frags (issue early; used after softmax): row d=l31 (+32), k=kv
        v8s vf0[4], vf1[4];
#pragma unroll
        for (int c = 0; c < 4; ++c) {
            vf0[c] = *(const v8s*)(VT + (size_t)l31*S_LEN      + kv0 + c*16 + hi*8);
            vf1[c] = *(const v8s*)(VT + (size_t)(32+l31)*S_LEN + kv0 + c*16 + hi*8);
        }

        // QK^T (swapped): S^T[kv][q]
        v16f s0t = zero16(), s1t = zero16();
#pragma unroll
        for (int dc = 0; dc < 4; ++dc) {
            s0t = __builtin_amdgcn_mfma_f32_32x32x16_bf16(kf0[dc], qf[dc], s0t, 0,0,0);
            s1t = __builtin_amdgcn_mfma_f32_32x32x16_bf16(kf1[dc], qf[dc], s1t, 0,0,0);
        }

        // in-register online softmax (q = l31; this lane holds 32 of 64 kv,
        // the other 32 live in lane^32)
        float tA = fmaxf(s0t[0], s0t[1]);
        float tB = fmaxf(s0t[2], s0t[3]);
#pragma unroll
        for (int r = 4; r < 16; r += 2) {
            tA = fmaxf(tA, s0t[r]);
            tB = fmaxf(tB, s0t[r+1]);
        }
#pragma unroll
        for (int r = 0; r < 16; r += 2) {
            tA = fmaxf(tA, s1t[r]);
            tB = fmaxf(tB, s1t[r+1]);
        }
        float tmax = fmaxf(tA, tB);
        tmax = fmaxf(tmax, __shfl_xor(tmax, 32));
        const float mnew = fmaxf(m, tmax);
        const float corr = __builtin_amdgcn_exp2f(m - mnew);
        m = mnew;

        float psA = 0.f, psB = 0.f;
#pragma unroll
        for (int r = 0; r < 16; ++r) {
            s0t[r] = __builtin_amdgcn_exp2f(s0t[r] - mnew);
            s1t[r] = __builtin_amdgcn_exp2f(s1t[r] - mnew);
            psA += s0t[r];
            psB += s1t[r];
        }
        float ps = psA + psB;
        ps += __shfl_xor(ps, 32);
        lsum = lsum * corr + ps;

        // rescale O^T: col q = l31 for every register -> uniform per-lane mul
#pragma unroll
        for (int r = 0; r < 16; ++r) { o0[r] *= corr; o1[r] *= corr; }

        // P -> bf16 frags. S^T reg r holds kv = (r&3)+8*(r>>2)+4*hi.
        // Frag chunk c needs kv = c*16 + hi*8 + j (j=0..7) as 4 u32 words:
        // cvt_pk pairs + permlane32_swap (hi half of x0x1 <-> lo half of x2x3).
        v8s pa[4];
#pragma unroll
        for (int c = 0; c < 4; ++c) {
            const int rb = (c & 1) * 8;
            unsigned x0, x1, x2, x3;
            if (c < 2) {
                x0 = cvtpk(s0t[rb+0], s0t[rb+1]);
                x1 = cvtpk(s0t[rb+2], s0t[rb+3]);
                x2 = cvtpk(s0t[rb+4], s0t[rb+5]);
                x3 = cvtpk(s0t[rb+6], s0t[rb+7]);
            } else {
                x0 = cvtpk(s1t[rb+0], s1t[rb+1]);
                x1 = cvtpk(s1t[rb+2], s1t[rb+3]);
                x2 = cvtpk(s1t[rb+4], s1t[rb+5]);
                x3 = cvtpk(s1t[rb+6], s1t[rb+7]);
            }
            pl32swap(x0, x2);
            pl32swap(x1, x3);
            v4u u;
            u[0] = x0; u[1] = x1; u[2] = x2; u[3] = x3;
            pa[c] = __builtin_bit_cast(v8s, u);
        }

        // PV transposed: O^T[d][q] += V^T[d][kv] * P^T[kv][q]
        // (A = V^T frags, B = P frags -- q stays lane-local in the output)
#pragma unroll
        for (int c = 0; c < 4; ++c) {
            o0 = __builtin_amdgcn_mfma_f32_32x32x16_bf16(vf0[c], pa[c], o0, 0,0,0);
            o1 = __builtin_amdgcn_mfma_f32_32x32x16_bf16(vf1[c], pa[c], o1, 0,0,0);
        }
    }

    // epilogue: normalize (per-lane, q = l31) and write
    // attn_buf[b][s0+l31][h*64 + d], d = reg row = (r&3)+8*(r>>2)+4*hi.
    // Regs 4c..4c+3 are 4 consecutive d -> one 8-byte store each.
    const int b = bh >> 3, h = bh & 7;
    const float inv = __builtin_amdgcn_rcpf(lsum);
    const size_t base = ((size_t)b * S_LEN + s0 + l31) * EMBED + h * HD;
#pragma unroll
    for (int c = 0; c < 4; ++c) {
        const int d0 = c*8 + hi*4;
        v4us p0, p1;
#pragma unroll
        for (int i = 0; i < 4; ++i) {
            p0[i] = (u16)f2bf(o0[c*4+i] * inv);
            p1[i] = (u16)f2bf(o1[c*4+i] * inv);
        }
        *(v4us*)(attn_buf + base + d0)      = p0;
        *(v4us*)(attn_buf + base + 32 + d0) = p1;
    }
}

// ---------------------------------------------------------------------------
// Kernel 3: out = attn_buf @ Wo^T + bo  (M=8192, N=512, K=512), fp32 out.
// ---------------------------------------------------------------------------
__global__ __launch_bounds__(256) void oproj_kernel(
    const u16* __restrict__ attn_buf, const u16* __restrict__ wo_bf,
    const float* __restrict__ bo, float* __restrict__ out)
{
    const int tid = threadIdx.x;
    const int lane = tid & 63;
    const int w = tid >> 6;
    const int lr = lane & 15;
    const int g  = lane >> 4;
    const int bid = blockIdx.x;
    const int m0 = (bid >> 3)*64 + w*16;
    const int n0 = (bid & 7)*64;

    v4f acc[4];
#pragma unroll
    for (int i = 0; i < 4; ++i) acc[i] = (v4f){0.f,0.f,0.f,0.f};

    for (int kk = 0; kk < EMBED/32; ++kk) {
        const int k0 = kk*32;
        v8s af = *(const v8s*)(attn_buf + (size_t)(m0+lr)*EMBED + k0 + g*8);
#pragma unroll
        for (int nt = 0; nt < 4; ++nt) {
            v8s bf = *(const v8s*)(wo_bf + (size_t)(n0 + nt*16 + lr)*EMBED + k0 + g*8);
            acc[nt] = __builtin_amdgcn_mfma_f32_16x16x32_bf16(af, bf, acc[nt], 0,0,0);
        }
    }
#pragma unroll
    for (int nt = 0; nt < 4; ++nt) {
        float bias = bo[n0 + nt*16 + lr];
#pragma unroll
        for (int r = 0; r < 4; ++r) {
            out[(size_t)(m0 + g*4 + r)*EMBED + n0 + nt*16 + lr] = acc[nt][r] + bias;
        }
    }
}

extern "C" void kernel_launch(void* const* d_in, const int* in_sizes, int n_in,
                              void* d_out, int out_size, void* d_ws, size_t ws_size,
                              hipStream_t stream)
{
    const float* xv = (const float*)d_in[0];   // values
    const float* xk = (const float*)d_in[1];   // keys
    const float* xq = (const float*)d_in[2];   // query
    const float* Wv = (const float*)d_in[3];
    const float* Wk = (const float*)d_in[4];
    const float* Wq = (const float*)d_in[5];
    const float* Wo = (const float*)d_in[6];
    const float* bo = (const float*)d_in[7];

    char* ws = (char*)d_ws;
    u16* q_bf   = (u16*)(ws + OFF_Q);
    u16* k_bf   = (u16*)(ws + OFF_K);
    u16* vt_bf  = (u16*)(ws + OFF_VT);
    u16* at_buf = (u16*)(ws + OFF_AT);
    u16* wo_bf  = (u16*)(ws + OFF_WO);

    proj_kernel<<<1024, 256, 0, stream>>>(xv, xk, xq, Wv, Wk, Wq, Wo,
                                          q_bf, k_bf, vt_bf, wo_bf);
    flash_kernel<<<512, 256, 0, stream>>>(q_bf, k_bf, vt_bf, at_buf);
    oproj_kernel<<<1024, 256, 0, stream>>>(at_buf, wo_bf, bo, (float*)d_out);
}